// Round 1
// baseline (303.541 us; speedup 1.0000x reference)
//
#include <hip/hip_runtime.h>

typedef __attribute__((ext_vector_type(8))) short short8;
typedef __attribute__((ext_vector_type(4))) short short4v;
typedef __attribute__((ext_vector_type(4))) float f32x4;

static constexpr int BATCH = 2, S = 2048, D = 1024, H = 16, DK = 64;
static constexpr int TOK = BATCH * S;     // 4096
static constexpr int NQKV = 3 * D;        // 3072
#define LOG2E 1.44269504088896340736f

__device__ inline unsigned short f2bf(float f) {
  unsigned int u = __builtin_bit_cast(unsigned int, f);
  unsigned int r = (u + 0x7fffu + ((u >> 16) & 1u)) >> 16;
  return (unsigned short)r;
}

__device__ inline void gload_lds16(const void* g, void* l) {
  __builtin_amdgcn_global_load_lds((const __attribute__((address_space(1))) void*)g,
                                   (__attribute__((address_space(3))) void*)l, 16, 0, 0);
}

// ---------------- fp32 -> bf16 elementwise ----------------
__global__ void k_cvt_bf16(const float* __restrict__ in, unsigned short* __restrict__ out, int n4) {
  int i = blockIdx.x * blockDim.x + threadIdx.x;
  if (i < n4) {
    float4 v = ((const float4*)in)[i];
    short4v o;
    o[0] = (short)f2bf(v.x); o[1] = (short)f2bf(v.y);
    o[2] = (short)f2bf(v.z); o[3] = (short)f2bf(v.w);
    ((short4v*)out)[i] = o;
  }
}

// ---------------- fp32 [R,C] -> bf16 [C,R] ----------------
__global__ void k_transpose_cvt(const float* __restrict__ in, unsigned short* __restrict__ out,
                                int R, int C) {
  __shared__ float tile[32][33];
  const int tx = threadIdx.x, ty = threadIdx.y;
  const int bc = blockIdx.x * 32, br = blockIdx.y * 32;
#pragma unroll
  for (int i = 0; i < 32; i += 8)
    tile[ty + i][tx] = in[(size_t)(br + ty + i) * C + bc + tx];
  __syncthreads();
#pragma unroll
  for (int i = 0; i < 32; i += 8)
    out[(size_t)(bc + ty + i) * R + br + tx] = f2bf(tile[tx][ty + i]);
}

// ---------------- V slice of qkv -> Vt[B*H, DK, S] ----------------
__global__ __launch_bounds__(256) void k_transpose_v(const unsigned short* __restrict__ qkv,
                                                     unsigned short* __restrict__ vt) {
  const int blk = blockIdx.x;
  const int stile = blk & 31, bh = blk >> 5;
  const int b = bh >> 4, h = bh & 15;
  const int s0 = stile * 64;
  __shared__ alignas(16) unsigned short tile[64][72];
  const int tid = threadIdx.x;
  const unsigned short* src = qkv + (size_t)(b * S + s0) * NQKV + 2 * D + h * DK;
#pragma unroll
  for (int it = 0; it < 2; ++it) {
    const int sl = it * 32 + (tid >> 3);
    const int d0 = (tid & 7) * 8;
    *(short8*)&tile[sl][d0] = *(const short8*)(src + (size_t)sl * NQKV + d0);
  }
  __syncthreads();
  const int d = tid >> 2, sg = tid & 3;
  short8 o0, o1;
#pragma unroll
  for (int j = 0; j < 8; ++j) {
    o0[j] = (short)tile[sg * 16 + j][d];
    o1[j] = (short)tile[sg * 16 + 8 + j][d];
  }
  unsigned short* dst = vt + (size_t)(bh * DK + d) * S + s0 + sg * 16;
  *(short8*)dst = o0;
  *(short8*)(dst + 8) = o1;
}

// ---------------- GEMM: A[M,K] bf16 @ Bt[N,K]^T + bias -> C[M,N] ----------------
template <int OUT_BF16>
__global__ __launch_bounds__(256, 2) void k_gemm(const unsigned short* __restrict__ A,
                                                 const unsigned short* __restrict__ Bt,
                                                 const float* __restrict__ bias,
                                                 void* __restrict__ Cout,
                                                 int M, int N, int K) {
  __shared__ alignas(16) unsigned short As[128 * 64];
  __shared__ alignas(16) unsigned short Bs[128 * 64];
  const int tid = threadIdx.x;
  const int wid = tid >> 6, lane = tid & 63;
  const int lr = lane & 15, lg = lane >> 4;
  const int nbx = N >> 7;
  const int bx = blockIdx.x % nbx, by = blockIdx.x / nbx;
  const int m0 = by << 7, n0 = bx << 7;
  const int wm = (wid >> 1) << 6, wn = (wid & 1) << 6;

  f32x4 acc[4][4] = {};

  // staging: chunk = c*4+wid (1KB each); row m = chunk*8 + lane/8;
  // source byte-in-row = ((lane&7)<<4) ^ ((lane>>3)<<4)  (pre-swizzled so reads can XOR)
  const int sk = ((lane & 7) ^ (lane >> 3)) << 4;
  const int srow = lane >> 3;

  const int ktc = K >> 6;
  for (int kt = 0; kt < ktc; ++kt) {
    const int k0 = kt << 6;
    __syncthreads();
#pragma unroll
    for (int c = 0; c < 4; ++c) {
      const int chunk = c * 4 + wid;
      const int mrow = chunk * 8 + srow;
      const char* ga = (const char*)(A + (size_t)(m0 + mrow) * K + k0) + sk;
      gload_lds16(ga, (char*)As + chunk * 1024);
      const char* gb = (const char*)(Bt + (size_t)(n0 + mrow) * K + k0) + sk;
      gload_lds16(gb, (char*)Bs + chunk * 1024);
    }
    __syncthreads();
#pragma unroll
    for (int ks = 0; ks < 2; ++ks) {
      const int kb = ks * 64 + lg * 16;
      const int swz = (lr & 7) << 4;
      short8 af[4], bfr[4];
#pragma unroll
      for (int mf = 0; mf < 4; ++mf) {
        const int m = wm + mf * 16 + lr;
        af[mf] = *(const short8*)((const char*)As + m * 128 + (kb ^ swz));
      }
#pragma unroll
      for (int nf = 0; nf < 4; ++nf) {
        const int n = wn + nf * 16 + lr;
        bfr[nf] = *(const short8*)((const char*)Bs + n * 128 + (kb ^ swz));
      }
#pragma unroll
      for (int mf = 0; mf < 4; ++mf)
#pragma unroll
        for (int nf = 0; nf < 4; ++nf)
          acc[mf][nf] = __builtin_amdgcn_mfma_f32_16x16x32_bf16(af[mf], bfr[nf], acc[mf][nf], 0, 0, 0);
    }
  }
#pragma unroll
  for (int nf = 0; nf < 4; ++nf) {
    const int n = n0 + wn + nf * 16 + lr;
    const float bv = bias[n];
#pragma unroll
    for (int mf = 0; mf < 4; ++mf) {
#pragma unroll
      for (int r = 0; r < 4; ++r) {
        const int m = m0 + wm + mf * 16 + lg * 4 + r;
        const float v = acc[mf][nf][r] + bv;
        if (OUT_BF16)
          ((unsigned short*)Cout)[(size_t)m * N + n] = f2bf(v);
        else
          ((float*)Cout)[(size_t)m * N + n] = v;
      }
    }
  }
}

// ---------------- flash attention ----------------
// grid = B*H*(S/64); 4 waves, each owns 16 q rows.
__global__ __launch_bounds__(256) void k_attn(const unsigned short* __restrict__ qkv,
                                              const unsigned short* __restrict__ vt,
                                              const int* __restrict__ mask,
                                              unsigned short* __restrict__ attn) {
  const int blk = blockIdx.x;
  const int qt = blk & 31;
  const int bh = blk >> 5;
  const int b = bh >> 4, h = bh & 15;
  const int tid = threadIdx.x;
  const int wid = tid >> 6, lane = tid & 63;
  const int lr = lane & 15, lg = lane >> 4;
  const int q0 = qt * 64 + wid * 16;

  __shared__ alignas(16) unsigned short P[4][16][72];

  const unsigned short* qrow = qkv + (size_t)(b * S + q0 + lr) * NQKV + h * DK;
  const short8 qf0 = *(const short8*)(qrow + lg * 8);
  const short8 qf1 = *(const short8*)(qrow + 32 + lg * 8);

  f32x4 o[4] = {};
  float mrun[4] = {-1e30f, -1e30f, -1e30f, -1e30f};
  float lrun[4] = {0.f, 0.f, 0.f, 0.f};

  const unsigned short* kcol = qkv + (size_t)b * S * NQKV + D + h * DK;
  const unsigned short* vbase = vt + (size_t)bh * DK * S;
  const int* mrow = mask + b * S;
  unsigned short* pw = &P[wid][0][0];

  for (int kt = 0; kt < S / 64; ++kt) {
    const int kbase = kt * 64;
    f32x4 sc[4];
#pragma unroll
    for (int kf = 0; kf < 4; ++kf) {
      const unsigned short* kp = kcol + (size_t)(kbase + kf * 16 + lr) * NQKV + lg * 8;
      const short8 k0 = *(const short8*)kp;
      const short8 k1 = *(const short8*)(kp + 32);
      f32x4 t = {};
      t = __builtin_amdgcn_mfma_f32_16x16x32_bf16(qf0, k0, t, 0, 0, 0);
      t = __builtin_amdgcn_mfma_f32_16x16x32_bf16(qf1, k1, t, 0, 0, 0);
      sc[kf] = t;
    }
    float pmax[4] = {-1e30f, -1e30f, -1e30f, -1e30f};
#pragma unroll
    for (int kf = 0; kf < 4; ++kf) {
      const int mv = mrow[kbase + kf * 16 + lr];
#pragma unroll
      for (int r = 0; r < 4; ++r) {
        const float v = (mv != 0) ? sc[kf][r] * 0.125f : -1e9f;
        sc[kf][r] = v;
        pmax[r] = fmaxf(pmax[r], v);
      }
    }
#pragma unroll
    for (int off = 1; off < 16; off <<= 1)
#pragma unroll
      for (int r = 0; r < 4; ++r)
        pmax[r] = fmaxf(pmax[r], __shfl_xor(pmax[r], off));
    float fac[4], lsum[4] = {0.f, 0.f, 0.f, 0.f};
#pragma unroll
    for (int r = 0; r < 4; ++r) {
      const float mnew = fmaxf(mrun[r], pmax[r]);
      fac[r] = exp2f((mrun[r] - mnew) * LOG2E);
      mrun[r] = mnew;
    }
#pragma unroll
    for (int kf = 0; kf < 4; ++kf)
#pragma unroll
      for (int r = 0; r < 4; ++r) {
        const float p = exp2f((sc[kf][r] - mrun[r]) * LOG2E);
        sc[kf][r] = p;
        lsum[r] += p;
      }
#pragma unroll
    for (int off = 1; off < 16; off <<= 1)
#pragma unroll
      for (int r = 0; r < 4; ++r)
        lsum[r] += __shfl_xor(lsum[r], off);
#pragma unroll
    for (int r = 0; r < 4; ++r)
      lrun[r] = lrun[r] * fac[r] + lsum[r];
#pragma unroll
    for (int df = 0; df < 4; ++df)
#pragma unroll
      for (int r = 0; r < 4; ++r)
        o[df][r] *= fac[r];
    // P (S-frag: row q = lg*4+r, col key = kf*16+lr) -> LDS, re-read as A-frag
#pragma unroll
    for (int kf = 0; kf < 4; ++kf)
#pragma unroll
      for (int r = 0; r < 4; ++r)
        pw[(lg * 4 + r) * 72 + kf * 16 + lr] = f2bf(sc[kf][r]);
    asm volatile("s_waitcnt lgkmcnt(0)" ::: "memory");
    const short8 pa0 = *(const short8*)((const char*)pw + lr * 144 + lg * 16);
    const short8 pa1 = *(const short8*)((const char*)pw + lr * 144 + 64 + lg * 16);
#pragma unroll
    for (int df = 0; df < 4; ++df) {
      const unsigned short* vp = vbase + (size_t)(df * 16 + lr) * S + kbase + lg * 8;
      const short8 v0 = *(const short8*)vp;
      const short8 v1 = *(const short8*)(vp + 32);
      o[df] = __builtin_amdgcn_mfma_f32_16x16x32_bf16(pa0, v0, o[df], 0, 0, 0);
      o[df] = __builtin_amdgcn_mfma_f32_16x16x32_bf16(pa1, v1, o[df], 0, 0, 0);
    }
  }
#pragma unroll
  for (int df = 0; df < 4; ++df)
#pragma unroll
    for (int r = 0; r < 4; ++r) {
      const int q = q0 + lg * 4 + r;
      attn[(size_t)(b * S + q) * D + h * DK + df * 16 + lr] = f2bf(o[df][r] / lrun[r]);
    }
}

extern "C" void kernel_launch(void* const* d_in, const int* in_sizes, int n_in,
                              void* d_out, int out_size, void* d_ws, size_t ws_size,
                              hipStream_t stream) {
  const float* x = (const float*)d_in[0];
  const int* mask = (const int*)d_in[1];
  const float* W_qkv = (const float*)d_in[2];
  const float* b_qkv = (const float*)d_in[3];
  const float* W_out = (const float*)d_in[4];
  const float* b_out = (const float*)d_in[5];
  float* out = (float*)d_out;

  char* ws = (char*)d_ws;
  unsigned short* x_bf   = (unsigned short*)(ws);                          // 8 MB
  unsigned short* wqkv_t = (unsigned short*)(ws + (size_t)(8 << 20));      // 6 MB
  unsigned short* wout_t = (unsigned short*)(ws + (size_t)(14 << 20));     // 2 MB
  unsigned short* qkv    = (unsigned short*)(ws + (size_t)(16 << 20));     // 24 MB
  unsigned short* vtr    = (unsigned short*)(ws + (size_t)(40 << 20));     // 8 MB
  unsigned short* attn   = (unsigned short*)(ws + (size_t)(48 << 20));     // 8 MB

  k_cvt_bf16<<<TOK * D / 4 / 256, 256, 0, stream>>>(x, x_bf, TOK * D / 4);
  k_transpose_cvt<<<dim3(NQKV / 32, D / 32), dim3(32, 8), 0, stream>>>(W_qkv, wqkv_t, D, NQKV);
  k_transpose_cvt<<<dim3(D / 32, D / 32), dim3(32, 8), 0, stream>>>(W_out, wout_t, D, D);
  k_gemm<1><<<(TOK / 128) * (NQKV / 128), 256, 0, stream>>>(x_bf, wqkv_t, b_qkv, qkv, TOK, NQKV, D);
  k_transpose_v<<<BATCH * H * (S / 64), 256, 0, stream>>>(qkv, vtr);
  k_attn<<<BATCH * H * (S / 64), 256, 0, stream>>>(qkv, vtr, mask, attn);
  k_gemm<0><<<(TOK / 128) * (D / 128), 256, 0, stream>>>(attn, wout_t, b_out, out, TOK, D, D);
}

// Round 2
// 191.223 us; speedup vs baseline: 1.5874x; 1.5874x over previous
//
#include <hip/hip_runtime.h>

typedef __attribute__((ext_vector_type(8))) short short8;
typedef __attribute__((ext_vector_type(4))) short short4v;
typedef __attribute__((ext_vector_type(4))) float f32x4;

static constexpr int BATCH = 2, S = 2048, D = 1024, H = 16, DK = 64;
static constexpr int TOK = BATCH * S;     // 4096
static constexpr int NQKV = 3 * D;        // 3072

__device__ inline unsigned short f2bf(float f) {
  unsigned int u = __builtin_bit_cast(unsigned int, f);
  unsigned int r = (u + 0x7fffu + ((u >> 16) & 1u)) >> 16;
  return (unsigned short)r;
}

__device__ inline void gload_lds16(const void* g, void* l) {
  __builtin_amdgcn_global_load_lds((const __attribute__((address_space(1))) void*)g,
                                   (__attribute__((address_space(3))) void*)l, 16, 0, 0);
}

// ---------------- fp32 -> bf16 elementwise ----------------
__global__ void k_cvt_bf16(const float* __restrict__ in, unsigned short* __restrict__ out, int n4) {
  int i = blockIdx.x * blockDim.x + threadIdx.x;
  if (i < n4) {
    float4 v = ((const float4*)in)[i];
    short4v o;
    o[0] = (short)f2bf(v.x); o[1] = (short)f2bf(v.y);
    o[2] = (short)f2bf(v.z); o[3] = (short)f2bf(v.w);
    ((short4v*)out)[i] = o;
  }
}

// ---------------- fp32 [R,C] -> bf16 [C,R] ----------------
__global__ void k_transpose_cvt(const float* __restrict__ in, unsigned short* __restrict__ out,
                                int R, int C) {
  __shared__ float tile[32][33];
  const int tx = threadIdx.x, ty = threadIdx.y;
  const int bc = blockIdx.x * 32, br = blockIdx.y * 32;
#pragma unroll
  for (int i = 0; i < 32; i += 8)
    tile[ty + i][tx] = in[(size_t)(br + ty + i) * C + bc + tx];
  __syncthreads();
#pragma unroll
  for (int i = 0; i < 32; i += 8)
    out[(size_t)(bc + ty + i) * R + br + tx] = f2bf(tile[tx][ty + i]);
}

// ---------------- V slice of qkv -> Vt[B*H, DK, S] ----------------
__global__ __launch_bounds__(256) void k_transpose_v(const unsigned short* __restrict__ qkv,
                                                     unsigned short* __restrict__ vt) {
  const int blk = blockIdx.x;
  const int stile = blk & 31, bh = blk >> 5;
  const int b = bh >> 4, h = bh & 15;
  const int s0 = stile * 64;
  __shared__ alignas(16) unsigned short tile[64][72];
  const int tid = threadIdx.x;
  const unsigned short* src = qkv + (size_t)(b * S + s0) * NQKV + 2 * D + h * DK;
#pragma unroll
  for (int it = 0; it < 2; ++it) {
    const int sl = it * 32 + (tid >> 3);
    const int d0 = (tid & 7) * 8;
    *(short8*)&tile[sl][d0] = *(const short8*)(src + (size_t)sl * NQKV + d0);
  }
  __syncthreads();
  const int d = tid >> 2, sg = tid & 3;
  short8 o0, o1;
#pragma unroll
  for (int j = 0; j < 8; ++j) {
    o0[j] = (short)tile[sg * 16 + j][d];
    o1[j] = (short)tile[sg * 16 + 8 + j][d];
  }
  unsigned short* dst = vt + (size_t)(bh * DK + d) * S + s0 + sg * 16;
  *(short8*)dst = o0;
  *(short8*)(dst + 8) = o1;
}

// ---------------- GEMM: A[M,K] bf16 @ Bt[N,K]^T + bias -> C[M,N] ----------------
template <int OUT_BF16>
__global__ __launch_bounds__(256, 2) void k_gemm(const unsigned short* __restrict__ A,
                                                 const unsigned short* __restrict__ Bt,
                                                 const float* __restrict__ bias,
                                                 void* __restrict__ Cout,
                                                 int M, int N, int K) {
  __shared__ alignas(16) unsigned short As[128 * 64];
  __shared__ alignas(16) unsigned short Bs[128 * 64];
  const int tid = threadIdx.x;
  const int wid = tid >> 6, lane = tid & 63;
  const int lr = lane & 15, lg = lane >> 4;
  const int nbx = N >> 7;
  const int bx = blockIdx.x % nbx, by = blockIdx.x / nbx;
  const int m0 = by << 7, n0 = bx << 7;
  const int wm = (wid >> 1) << 6, wn = (wid & 1) << 6;

  f32x4 acc[4][4] = {};

  const int sk = ((lane & 7) ^ (lane >> 3)) << 4;
  const int srow = lane >> 3;

  const int ktc = K >> 6;
  for (int kt = 0; kt < ktc; ++kt) {
    const int k0 = kt << 6;
    __syncthreads();
#pragma unroll
    for (int c = 0; c < 4; ++c) {
      const int chunk = c * 4 + wid;
      const int mrow = chunk * 8 + srow;
      const char* ga = (const char*)(A + (size_t)(m0 + mrow) * K + k0) + sk;
      gload_lds16(ga, (char*)As + chunk * 1024);
      const char* gb = (const char*)(Bt + (size_t)(n0 + mrow) * K + k0) + sk;
      gload_lds16(gb, (char*)Bs + chunk * 1024);
    }
    __syncthreads();
#pragma unroll
    for (int ks = 0; ks < 2; ++ks) {
      const int kb = ks * 64 + lg * 16;
      const int swz = (lr & 7) << 4;
      short8 af[4], bfr[4];
#pragma unroll
      for (int mf = 0; mf < 4; ++mf) {
        const int m = wm + mf * 16 + lr;
        af[mf] = *(const short8*)((const char*)As + m * 128 + (kb ^ swz));
      }
#pragma unroll
      for (int nf = 0; nf < 4; ++nf) {
        const int n = wn + nf * 16 + lr;
        bfr[nf] = *(const short8*)((const char*)Bs + n * 128 + (kb ^ swz));
      }
#pragma unroll
      for (int mf = 0; mf < 4; ++mf)
#pragma unroll
        for (int nf = 0; nf < 4; ++nf)
          acc[mf][nf] = __builtin_amdgcn_mfma_f32_16x16x32_bf16(af[mf], bfr[nf], acc[mf][nf], 0, 0, 0);
    }
  }
#pragma unroll
  for (int nf = 0; nf < 4; ++nf) {
    const int n = n0 + wn + nf * 16 + lr;
    const float bv = bias[n];
#pragma unroll
    for (int mf = 0; mf < 4; ++mf) {
#pragma unroll
      for (int r = 0; r < 4; ++r) {
        const int m = m0 + wm + mf * 16 + lg * 4 + r;
        const float v = acc[mf][nf][r] + bv;
        if (OUT_BF16)
          ((unsigned short*)Cout)[(size_t)m * N + n] = f2bf(v);
        else
          ((float*)Cout)[(size_t)m * N + n] = v;
      }
    }
  }
}

// ---------------- flash attention v2 ----------------
// grid = B*H*(S/128) = 512 blocks; 4 waves, each owns 32 q rows.
// K/V tiles (64 keys) staged in LDS (double-buffered, XOR-swizzled), shared by all waves.
__global__ __launch_bounds__(256, 2) void k_attn(const unsigned short* __restrict__ qkv,
                                                 const unsigned short* __restrict__ vt,
                                                 const int* __restrict__ mask,
                                                 unsigned short* __restrict__ attn) {
  __shared__ alignas(16) char Ks[2][8192];   // [64 keys][128B], xor-swizzled
  __shared__ alignas(16) char Vs[2][8192];   // [64 d][128B keys], xor-swizzled
  __shared__ alignas(16) unsigned short P[4][32][72];
  __shared__ float msk[S];

  const int blk = blockIdx.x;
  // XCD-chunked swizzle: dispatch p (-> XCD p%8) processes work (p%8)*64 + p/8
  const int work = (blk & 7) * 64 + (blk >> 3);
  const int qt = work & 15;
  const int bh = work >> 4;
  const int b = bh >> 4, h = bh & 15;
  const int tid = threadIdx.x;
  const int wid = tid >> 6, lane = tid & 63;
  const int lr = lane & 15, lg = lane >> 4;
  const int q0 = qt * 128 + wid * 32;

  // mask -> additive table in log2 domain
  for (int i = tid; i < S; i += 256)
    msk[i] = mask[b * S + i] ? 0.f : -3.0e9f;

  // Q fragments (2 m-frags x 2 k-slices), held in registers
  const unsigned short* qbase = qkv + (size_t)(b * S + q0) * NQKV + h * DK;
  short8 qf[2][2];
#pragma unroll
  for (int mq = 0; mq < 2; ++mq)
#pragma unroll
    for (int ks = 0; ks < 2; ++ks)
      qf[mq][ks] = *(const short8*)(qbase + (size_t)(mq * 16 + lr) * NQKV + ks * 32 + lg * 8);

  const unsigned short* kg0 = qkv + ((size_t)b * S * NQKV + D + h * DK);
  const unsigned short* vg0 = vt + (size_t)bh * DK * S;
  const int srow = lane >> 3;
  const int sk = ((lane & 7) ^ srow) << 4;

  auto stage = [&](int buf, int kt) {
    const int kbase = kt * 64;
    const unsigned short* kg = kg0 + (size_t)kbase * NQKV;
    const unsigned short* vg = vg0 + kbase;
#pragma unroll
    for (int c = 0; c < 2; ++c) {
      const int chunk = wid + c * 4;
      const int row = chunk * 8 + srow;
      gload_lds16((const char*)(kg + (size_t)row * NQKV) + sk, Ks[buf] + chunk * 1024);
      gload_lds16((const char*)(vg + (size_t)row * S) + sk, Vs[buf] + chunk * 1024);
    }
  };

  f32x4 o[2][4] = {};
  float m2[2][4], lrun[2][4];
#pragma unroll
  for (int mq = 0; mq < 2; ++mq)
#pragma unroll
    for (int r = 0; r < 4; ++r) { m2[mq][r] = -1e30f; lrun[mq][r] = 0.f; }

  stage(0, 0);
  __syncthreads();

  constexpr float C2 = 0.125f * 1.44269504088896f;  // scale * log2(e)
  const int rswz = (lr & 7) << 4;
  unsigned short* pw = &P[wid][0][0];
  int cur = 0;

  for (int kt = 0; kt < S / 64; ++kt) {
    if (kt + 1 < S / 64) stage(cur ^ 1, kt + 1);
    const int kbase = kt * 64;

    // K B-frags from LDS
    short8 kfr[4][2];
#pragma unroll
    for (int kf = 0; kf < 4; ++kf)
#pragma unroll
      for (int ks = 0; ks < 2; ++ks)
        kfr[kf][ks] = *(const short8*)(Ks[cur] + (kf * 16 + lr) * 128 + ((ks * 64 + lg * 16) ^ rswz));

    // QK^T
    f32x4 sc[2][4];
#pragma unroll
    for (int mq = 0; mq < 2; ++mq)
#pragma unroll
      for (int kf = 0; kf < 4; ++kf) {
        f32x4 t = {};
        t = __builtin_amdgcn_mfma_f32_16x16x32_bf16(qf[mq][0], kfr[kf][0], t, 0, 0, 0);
        t = __builtin_amdgcn_mfma_f32_16x16x32_bf16(qf[mq][1], kfr[kf][1], t, 0, 0, 0);
        sc[mq][kf] = t;
      }

    // scale + mask (log2 domain)
    float add_[4];
#pragma unroll
    for (int kf = 0; kf < 4; ++kf) add_[kf] = msk[kbase + kf * 16 + lr];
#pragma unroll
    for (int mq = 0; mq < 2; ++mq)
#pragma unroll
      for (int kf = 0; kf < 4; ++kf)
#pragma unroll
        for (int r = 0; r < 4; ++r)
          sc[mq][kf][r] = sc[mq][kf][r] * C2 + add_[kf];

    // row max
    float pmax[2][4];
#pragma unroll
    for (int mq = 0; mq < 2; ++mq)
#pragma unroll
      for (int r = 0; r < 4; ++r)
        pmax[mq][r] = fmaxf(fmaxf(sc[mq][0][r], sc[mq][1][r]), fmaxf(sc[mq][2][r], sc[mq][3][r]));
#pragma unroll
    for (int off = 1; off < 16; off <<= 1)
#pragma unroll
      for (int mq = 0; mq < 2; ++mq)
#pragma unroll
        for (int r = 0; r < 4; ++r)
          pmax[mq][r] = fmaxf(pmax[mq][r], __shfl_xor(pmax[mq][r], off));

    // running max update + rescale factor
    float fac[2][4];
#pragma unroll
    for (int mq = 0; mq < 2; ++mq)
#pragma unroll
      for (int r = 0; r < 4; ++r) {
        const float mnew = fmaxf(m2[mq][r], pmax[mq][r]);
        fac[mq][r] = exp2f(m2[mq][r] - mnew);
        m2[mq][r] = mnew;
      }

    // p = exp2(sc - m), row sums
    float ls[2][4] = {};
#pragma unroll
    for (int mq = 0; mq < 2; ++mq)
#pragma unroll
      for (int kf = 0; kf < 4; ++kf)
#pragma unroll
        for (int r = 0; r < 4; ++r) {
          const float p = exp2f(sc[mq][kf][r] - m2[mq][r]);
          sc[mq][kf][r] = p;
          ls[mq][r] += p;
        }
#pragma unroll
    for (int off = 1; off < 16; off <<= 1)
#pragma unroll
      for (int mq = 0; mq < 2; ++mq)
#pragma unroll
        for (int r = 0; r < 4; ++r)
          ls[mq][r] += __shfl_xor(ls[mq][r], off);
#pragma unroll
    for (int mq = 0; mq < 2; ++mq)
#pragma unroll
      for (int r = 0; r < 4; ++r)
        lrun[mq][r] = lrun[mq][r] * fac[mq][r] + ls[mq][r];

    // rescale O
#pragma unroll
    for (int mq = 0; mq < 2; ++mq)
#pragma unroll
      for (int df = 0; df < 4; ++df)
#pragma unroll
        for (int r = 0; r < 4; ++r)
          o[mq][df][r] *= fac[mq][r];

    // P (row q, col key) -> per-wave LDS, re-read as A-frags
#pragma unroll
    for (int mq = 0; mq < 2; ++mq)
#pragma unroll
      for (int kf = 0; kf < 4; ++kf)
#pragma unroll
        for (int r = 0; r < 4; ++r)
          pw[(mq * 16 + lg * 4 + r) * 72 + kf * 16 + lr] = f2bf(sc[mq][kf][r]);
    asm volatile("s_waitcnt lgkmcnt(0)" ::: "memory");
    short8 pa[2][2];
#pragma unroll
    for (int mq = 0; mq < 2; ++mq)
#pragma unroll
      for (int ks = 0; ks < 2; ++ks)
        pa[mq][ks] = *(const short8*)((const char*)&P[wid][mq * 16 + lr][0] + ks * 64 + lg * 16);

    // V B-frags + PV
#pragma unroll
    for (int df = 0; df < 4; ++df) {
      short8 v0 = *(const short8*)(Vs[cur] + (df * 16 + lr) * 128 + ((0 + lg * 16) ^ rswz));
      short8 v1 = *(const short8*)(Vs[cur] + (df * 16 + lr) * 128 + ((64 + lg * 16) ^ rswz));
#pragma unroll
      for (int mq = 0; mq < 2; ++mq) {
        o[mq][df] = __builtin_amdgcn_mfma_f32_16x16x32_bf16(pa[mq][0], v0, o[mq][df], 0, 0, 0);
        o[mq][df] = __builtin_amdgcn_mfma_f32_16x16x32_bf16(pa[mq][1], v1, o[mq][df], 0, 0, 0);
      }
    }

    __syncthreads();
    cur ^= 1;
  }

  // epilogue: normalize + store
#pragma unroll
  for (int mq = 0; mq < 2; ++mq) {
    float inv[4];
#pragma unroll
    for (int r = 0; r < 4; ++r) inv[r] = 1.0f / lrun[mq][r];
#pragma unroll
    for (int df = 0; df < 4; ++df)
#pragma unroll
      for (int r = 0; r < 4; ++r) {
        const int q = q0 + mq * 16 + lg * 4 + r;
        attn[(size_t)(b * S + q) * D + h * DK + df * 16 + lr] = f2bf(o[mq][df][r] * inv[r]);
      }
  }
}

extern "C" void kernel_launch(void* const* d_in, const int* in_sizes, int n_in,
                              void* d_out, int out_size, void* d_ws, size_t ws_size,
                              hipStream_t stream) {
  const float* x = (const float*)d_in[0];
  const int* mask = (const int*)d_in[1];
  const float* W_qkv = (const float*)d_in[2];
  const float* b_qkv = (const float*)d_in[3];
  const float* W_out = (const float*)d_in[4];
  const float* b_out = (const float*)d_in[5];
  float* out = (float*)d_out;

  char* ws = (char*)d_ws;
  unsigned short* x_bf   = (unsigned short*)(ws);                          // 8 MB
  unsigned short* wqkv_t = (unsigned short*)(ws + (size_t)(8 << 20));      // 6 MB
  unsigned short* wout_t = (unsigned short*)(ws + (size_t)(14 << 20));     // 2 MB
  unsigned short* qkv    = (unsigned short*)(ws + (size_t)(16 << 20));     // 24 MB
  unsigned short* vtr    = (unsigned short*)(ws + (size_t)(40 << 20));     // 8 MB
  unsigned short* attn   = (unsigned short*)(ws + (size_t)(48 << 20));     // 8 MB

  k_cvt_bf16<<<TOK * D / 4 / 256, 256, 0, stream>>>(x, x_bf, TOK * D / 4);
  k_transpose_cvt<<<dim3(NQKV / 32, D / 32), dim3(32, 8), 0, stream>>>(W_qkv, wqkv_t, D, NQKV);
  k_transpose_cvt<<<dim3(D / 32, D / 32), dim3(32, 8), 0, stream>>>(W_out, wout_t, D, D);
  k_gemm<1><<<(TOK / 128) * (NQKV / 128), 256, 0, stream>>>(x_bf, wqkv_t, b_qkv, qkv, TOK, NQKV, D);
  k_transpose_v<<<BATCH * H * (S / 64), 256, 0, stream>>>(qkv, vtr);
  k_attn<<<BATCH * H * (S / 128), 256, 0, stream>>>(qkv, vtr, mask, attn);
  k_gemm<0><<<(TOK / 128) * (D / 128), 256, 0, stream>>>(attn, wout_t, b_out, out, TOK, D, D);
}

// Round 3
// 135.396 us; speedup vs baseline: 2.2419x; 1.4123x over previous
//
#include <hip/hip_runtime.h>
#include <hip/hip_bf16.h>

typedef __attribute__((ext_vector_type(8))) short short8;
typedef __attribute__((ext_vector_type(4))) short short4v;
typedef __attribute__((ext_vector_type(4))) float f32x4;

static constexpr int BATCH = 2, S = 2048, D = 1024, H = 16, DK = 64;
static constexpr int TOK = BATCH * S;     // 4096
static constexpr int NQKV = 3 * D;        // 3072

__device__ inline unsigned short f2bf(float f) {
  unsigned int u = __builtin_bit_cast(unsigned int, f);
  unsigned int r = (u + 0x7fffu + ((u >> 16) & 1u)) >> 16;
  return (unsigned short)r;
}

__device__ inline unsigned short f2bf_fast(float f) {
  return __builtin_bit_cast(unsigned short, __float2bfloat16(f));
}

__device__ inline float fexp2(float x) { return __builtin_amdgcn_exp2f(x); }

__device__ inline void gload_lds16(const void* g, void* l) {
  __builtin_amdgcn_global_load_lds((const __attribute__((address_space(1))) void*)g,
                                   (__attribute__((address_space(3))) void*)l, 16, 0, 0);
}

// ---------------- fp32 -> bf16 elementwise (+ mask additive table) ----------------
__global__ void k_cvt_bf16(const float* __restrict__ in, unsigned short* __restrict__ out,
                           int n4, const int* __restrict__ mask, float* __restrict__ maskadd,
                           int nmask) {
  const int cvtBlocks = n4 >> 8;
  if ((int)blockIdx.x < cvtBlocks) {
    int i = blockIdx.x * 256 + threadIdx.x;
    float4 v = ((const float4*)in)[i];
    short4v o;
    o[0] = (short)f2bf(v.x); o[1] = (short)f2bf(v.y);
    o[2] = (short)f2bf(v.z); o[3] = (short)f2bf(v.w);
    ((short4v*)out)[i] = o;
  } else {
    int j = (blockIdx.x - cvtBlocks) * 256 + threadIdx.x;
    if (j < nmask) maskadd[j] = mask[j] ? 0.f : -1.0e9f;
  }
}

// ---------------- fp32 [R,C] -> bf16 [C,R] ----------------
__global__ void k_transpose_cvt(const float* __restrict__ in, unsigned short* __restrict__ out,
                                int R, int C) {
  __shared__ float tile[32][33];
  const int tx = threadIdx.x, ty = threadIdx.y;
  const int bc = blockIdx.x * 32, br = blockIdx.y * 32;
#pragma unroll
  for (int i = 0; i < 32; i += 8)
    tile[ty + i][tx] = in[(size_t)(br + ty + i) * C + bc + tx];
  __syncthreads();
#pragma unroll
  for (int i = 0; i < 32; i += 8)
    out[(size_t)(bc + ty + i) * R + br + tx] = f2bf(tile[tx][ty + i]);
}

// ---------------- V slice of qkv -> Vt[B*H, DK, S] ----------------
__global__ __launch_bounds__(256) void k_transpose_v(const unsigned short* __restrict__ qkv,
                                                     unsigned short* __restrict__ vt) {
  const int blk = blockIdx.x;
  const int stile = blk & 31, bh = blk >> 5;
  const int b = bh >> 4, h = bh & 15;
  const int s0 = stile * 64;
  __shared__ alignas(16) unsigned short tile[64][72];
  const int tid = threadIdx.x;
  const unsigned short* src = qkv + (size_t)(b * S + s0) * NQKV + 2 * D + h * DK;
#pragma unroll
  for (int it = 0; it < 2; ++it) {
    const int sl = it * 32 + (tid >> 3);
    const int d0 = (tid & 7) * 8;
    *(short8*)&tile[sl][d0] = *(const short8*)(src + (size_t)sl * NQKV + d0);
  }
  __syncthreads();
  const int d = tid >> 2, sg = tid & 3;
  short8 o0, o1;
#pragma unroll
  for (int j = 0; j < 8; ++j) {
    o0[j] = (short)tile[sg * 16 + j][d];
    o1[j] = (short)tile[sg * 16 + 8 + j][d];
  }
  unsigned short* dst = vt + (size_t)(bh * DK + d) * S + s0 + sg * 16;
  *(short8*)dst = o0;
  *(short8*)(dst + 8) = o1;
}

// ---------------- GEMM: A[M,K] bf16 @ Bt[N,K]^T + bias -> C[M,N] ----------------
template <int OUT_BF16>
__global__ __launch_bounds__(256, 2) void k_gemm(const unsigned short* __restrict__ A,
                                                 const unsigned short* __restrict__ Bt,
                                                 const float* __restrict__ bias,
                                                 void* __restrict__ Cout,
                                                 int M, int N, int K) {
  __shared__ alignas(16) unsigned short As[128 * 64];
  __shared__ alignas(16) unsigned short Bs[128 * 64];
  const int tid = threadIdx.x;
  const int wid = tid >> 6, lane = tid & 63;
  const int lr = lane & 15, lg = lane >> 4;
  const int nbx = N >> 7;
  const int bx = blockIdx.x % nbx, by = blockIdx.x / nbx;
  const int m0 = by << 7, n0 = bx << 7;
  const int wm = (wid >> 1) << 6, wn = (wid & 1) << 6;

  f32x4 acc[4][4] = {};

  const int sk = ((lane & 7) ^ (lane >> 3)) << 4;
  const int srow = lane >> 3;

  const int ktc = K >> 6;
  for (int kt = 0; kt < ktc; ++kt) {
    const int k0 = kt << 6;
    __syncthreads();
#pragma unroll
    for (int c = 0; c < 4; ++c) {
      const int chunk = c * 4 + wid;
      const int mrow = chunk * 8 + srow;
      const char* ga = (const char*)(A + (size_t)(m0 + mrow) * K + k0) + sk;
      gload_lds16(ga, (char*)As + chunk * 1024);
      const char* gb = (const char*)(Bt + (size_t)(n0 + mrow) * K + k0) + sk;
      gload_lds16(gb, (char*)Bs + chunk * 1024);
    }
    __syncthreads();
#pragma unroll
    for (int ks = 0; ks < 2; ++ks) {
      const int kb = ks * 64 + lg * 16;
      const int swz = (lr & 7) << 4;
      short8 af[4], bfr[4];
#pragma unroll
      for (int mf = 0; mf < 4; ++mf) {
        const int m = wm + mf * 16 + lr;
        af[mf] = *(const short8*)((const char*)As + m * 128 + (kb ^ swz));
      }
#pragma unroll
      for (int nf = 0; nf < 4; ++nf) {
        const int n = wn + nf * 16 + lr;
        bfr[nf] = *(const short8*)((const char*)Bs + n * 128 + (kb ^ swz));
      }
#pragma unroll
      for (int mf = 0; mf < 4; ++mf)
#pragma unroll
        for (int nf = 0; nf < 4; ++nf)
          acc[mf][nf] = __builtin_amdgcn_mfma_f32_16x16x32_bf16(af[mf], bfr[nf], acc[mf][nf], 0, 0, 0);
    }
  }
#pragma unroll
  for (int nf = 0; nf < 4; ++nf) {
    const int n = n0 + wn + nf * 16 + lr;
    const float bv = bias[n];
#pragma unroll
    for (int mf = 0; mf < 4; ++mf) {
#pragma unroll
      for (int r = 0; r < 4; ++r) {
        const int m = m0 + wm + mf * 16 + lg * 4 + r;
        const float v = acc[mf][nf][r] + bv;
        if (OUT_BF16)
          ((unsigned short*)Cout)[(size_t)m * N + n] = f2bf(v);
        else
          ((float*)Cout)[(size_t)m * N + n] = v;
      }
    }
  }
}

// ---------------- flash attention v3 ----------------
// grid = B*H*(S/128) = 512 blocks; 8 waves x 16 q rows.
// K/V tiles (64 keys) in LDS (double-buffered, XOR-swizzled); defer-max softmax,
// per-lane partial l-sums reduced once in epilogue.
__global__ __launch_bounds__(512, 4) void k_attn(const unsigned short* __restrict__ qkv,
                                                 const unsigned short* __restrict__ vt,
                                                 const float* __restrict__ maskadd,
                                                 unsigned short* __restrict__ attn) {
  __shared__ alignas(16) char Ks[2][8192];   // [64 keys][128B], xor-swizzled
  __shared__ alignas(16) char Vs[2][8192];   // [64 d][128B keys], xor-swizzled
  __shared__ alignas(16) unsigned short P[8][16][72];

  const int blk = blockIdx.x;
  // XCD-chunked swizzle (512 = 8*64, bijective): XCD x gets 4 consecutive (b,h)
  const int work = (blk & 7) * 64 + (blk >> 3);
  const int qt = work & 15;
  const int bh = work >> 4;
  const int b = bh >> 4, h = bh & 15;
  const int tid = threadIdx.x;
  const int wid = tid >> 6, lane = tid & 63;
  const int lr = lane & 15, lg = lane >> 4;
  const int q0 = qt * 128 + wid * 16;

  // Q fragments (2 k-slices) in registers
  const unsigned short* qbase = qkv + (size_t)(b * S + q0) * NQKV + h * DK;
  short8 qf[2];
#pragma unroll
  for (int ks = 0; ks < 2; ++ks)
    qf[ks] = *(const short8*)(qbase + (size_t)lr * NQKV + ks * 32 + lg * 8);

  const unsigned short* kg0 = qkv + ((size_t)b * S * NQKV + D + h * DK);
  const unsigned short* vg0 = vt + (size_t)bh * DK * S;
  const float* madd = maskadd + b * S;
  const int srow = lane >> 3;
  const int sk = ((lane & 7) ^ srow) << 4;

  auto stage = [&](int buf, int kt) {
    const int kbase = kt * 64;
    const int row = wid * 8 + srow;
    gload_lds16((const char*)(kg0 + (size_t)(kbase + row) * NQKV) + sk, Ks[buf] + row * 128);
    gload_lds16((const char*)(vg0 + (size_t)row * S + kbase) + sk, Vs[buf] + row * 128);
  };

  f32x4 o[4] = {};
  float m2[4] = {-1e30f, -1e30f, -1e30f, -1e30f};
  float lpart[4] = {0.f, 0.f, 0.f, 0.f};  // per-lane partial row sums

  stage(0, 0);
  __syncthreads();

  constexpr float C2 = 0.125f * 1.44269504088896f;  // scale * log2(e)
  const int rswz = (lr & 7) << 4;
  unsigned short* pw = &P[wid][0][0];
  int cur = 0;

  for (int kt = 0; kt < S / 64; ++kt) {
    if (kt + 1 < S / 64) stage(cur ^ 1, kt + 1);
    const int kbase = kt * 64;

    // mask adds (L2-resident table), issued early
    float add_[4];
#pragma unroll
    for (int kf = 0; kf < 4; ++kf) add_[kf] = madd[kbase + kf * 16 + lr];

    // K B-frags from LDS
    short8 kfr[4][2];
#pragma unroll
    for (int kf = 0; kf < 4; ++kf)
#pragma unroll
      for (int ks = 0; ks < 2; ++ks)
        kfr[kf][ks] = *(const short8*)(Ks[cur] + (kf * 16 + lr) * 128 + ((ks * 64 + lg * 16) ^ rswz));

    // QK^T  (log2 domain scores)
    f32x4 sc[4];
#pragma unroll
    for (int kf = 0; kf < 4; ++kf) {
      f32x4 t = {};
      t = __builtin_amdgcn_mfma_f32_16x16x32_bf16(qf[0], kfr[kf][0], t, 0, 0, 0);
      t = __builtin_amdgcn_mfma_f32_16x16x32_bf16(qf[1], kfr[kf][1], t, 0, 0, 0);
      sc[kf] = t;
    }
#pragma unroll
    for (int kf = 0; kf < 4; ++kf)
#pragma unroll
      for (int r = 0; r < 4; ++r)
        sc[kf][r] = sc[kf][r] * C2 + add_[kf];

    // per-lane row-partial max; wave-uniform defer-max vote (THR = 6 in log2 domain)
    float pmax[4];
#pragma unroll
    for (int r = 0; r < 4; ++r)
      pmax[r] = fmaxf(fmaxf(sc[0][r], sc[1][r]), fmaxf(sc[2][r], sc[3][r]));
    float worst = fmaxf(fmaxf(pmax[0] - m2[0], pmax[1] - m2[1]),
                        fmaxf(pmax[2] - m2[2], pmax[3] - m2[3]));
    if (!__all(worst <= 6.0f)) {
      // rare path: true row max, rescale O and partial sums
#pragma unroll
      for (int r = 0; r < 4; ++r) {
        float pm = pmax[r];
#pragma unroll
        for (int off = 1; off < 16; off <<= 1) pm = fmaxf(pm, __shfl_xor(pm, off));
        const float mnew = fmaxf(m2[r], pm);
        const float fac = fexp2(m2[r] - mnew);
        m2[r] = mnew;
        lpart[r] *= fac;
#pragma unroll
        for (int df = 0; df < 4; ++df) o[df][r] *= fac;
      }
    }

    // p = exp2(sc - m), accumulate per-lane partial sums
#pragma unroll
    for (int kf = 0; kf < 4; ++kf)
#pragma unroll
      for (int r = 0; r < 4; ++r) {
        const float p = fexp2(sc[kf][r] - m2[r]);
        sc[kf][r] = p;
        lpart[r] += p;
      }

    // V B-frags (independent of P round-trip; issue early)
    short8 vfr[4][2];
#pragma unroll
    for (int df = 0; df < 4; ++df)
#pragma unroll
      for (int ks = 0; ks < 2; ++ks)
        vfr[df][ks] = *(const short8*)(Vs[cur] + (df * 16 + lr) * 128 + ((ks * 64 + lg * 16) ^ rswz));

    // P -> per-wave LDS (row q, col key), re-read as A-frags
#pragma unroll
    for (int kf = 0; kf < 4; ++kf)
#pragma unroll
      for (int r = 0; r < 4; ++r)
        pw[(lg * 4 + r) * 72 + kf * 16 + lr] = f2bf_fast(sc[kf][r]);
    asm volatile("s_waitcnt lgkmcnt(0)" ::: "memory");
    short8 pa[2];
#pragma unroll
    for (int ks = 0; ks < 2; ++ks)
      pa[ks] = *(const short8*)((const char*)&P[wid][lr][0] + ks * 64 + lg * 16);

    // PV
#pragma unroll
    for (int df = 0; df < 4; ++df) {
      o[df] = __builtin_amdgcn_mfma_f32_16x16x32_bf16(pa[0], vfr[df][0], o[df], 0, 0, 0);
      o[df] = __builtin_amdgcn_mfma_f32_16x16x32_bf16(pa[1], vfr[df][1], o[df], 0, 0, 0);
    }

    __syncthreads();
    cur ^= 1;
  }

  // epilogue: one shfl-reduce of the partial sums, normalize, store
  float lrun[4];
#pragma unroll
  for (int r = 0; r < 4; ++r) {
    float s = lpart[r];
#pragma unroll
    for (int off = 1; off < 16; off <<= 1) s += __shfl_xor(s, off);
    lrun[r] = 1.0f / s;
  }
#pragma unroll
  for (int df = 0; df < 4; ++df)
#pragma unroll
    for (int r = 0; r < 4; ++r) {
      const int q = q0 + lg * 4 + r;
      attn[(size_t)(b * S + q) * D + h * DK + df * 16 + lr] = f2bf(o[df][r] * lrun[r]);
    }
}

extern "C" void kernel_launch(void* const* d_in, const int* in_sizes, int n_in,
                              void* d_out, int out_size, void* d_ws, size_t ws_size,
                              hipStream_t stream) {
  const float* x = (const float*)d_in[0];
  const int* mask = (const int*)d_in[1];
  const float* W_qkv = (const float*)d_in[2];
  const float* b_qkv = (const float*)d_in[3];
  const float* W_out = (const float*)d_in[4];
  const float* b_out = (const float*)d_in[5];
  float* out = (float*)d_out;

  char* ws = (char*)d_ws;
  unsigned short* x_bf   = (unsigned short*)(ws);                          // 8 MB
  unsigned short* wqkv_t = (unsigned short*)(ws + (size_t)(8 << 20));      // 6 MB
  unsigned short* wout_t = (unsigned short*)(ws + (size_t)(14 << 20));     // 2 MB
  unsigned short* qkv    = (unsigned short*)(ws + (size_t)(16 << 20));     // 24 MB
  unsigned short* vtr    = (unsigned short*)(ws + (size_t)(40 << 20));     // 8 MB
  unsigned short* attn   = (unsigned short*)(ws + (size_t)(48 << 20));     // 8 MB
  float*          madd   = (float*)(ws + (size_t)(56 << 20));              // 16 KB

  const int n4 = TOK * D / 4;
  k_cvt_bf16<<<n4 / 256 + (TOK + 255) / 256, 256, 0, stream>>>(x, x_bf, n4, mask, madd, TOK);
  k_transpose_cvt<<<dim3(NQKV / 32, D / 32), dim3(32, 8), 0, stream>>>(W_qkv, wqkv_t, D, NQKV);
  k_transpose_cvt<<<dim3(D / 32, D / 32), dim3(32, 8), 0, stream>>>(W_out, wout_t, D, D);
  k_gemm<1><<<(TOK / 128) * (NQKV / 128), 256, 0, stream>>>(x_bf, wqkv_t, b_qkv, qkv, TOK, NQKV, D);
  k_transpose_v<<<BATCH * H * (S / 64), 256, 0, stream>>>(qkv, vtr);
  k_attn<<<BATCH * H * (S / 128), 512, 0, stream>>>(qkv, vtr, madd, attn);
  k_gemm<0><<<(TOK / 128) * (D / 128), 256, 0, stream>>>(attn, wout_t, b_out, out, TOK, D, D);
}

// Round 4
// 132.979 us; speedup vs baseline: 2.2826x; 1.0182x over previous
//
#include <hip/hip_runtime.h>
#include <hip/hip_bf16.h>

typedef __attribute__((ext_vector_type(8))) short short8;
typedef __attribute__((ext_vector_type(4))) short short4v;
typedef __attribute__((ext_vector_type(4))) float f32x4;

static constexpr int BATCH = 2, S = 2048, D = 1024, H = 16, DK = 64;
static constexpr int TOK = BATCH * S;     // 4096
static constexpr int NQKV = 3 * D;        // 3072

__device__ inline unsigned short f2bf(float f) {
  unsigned int u = __builtin_bit_cast(unsigned int, f);
  unsigned int r = (u + 0x7fffu + ((u >> 16) & 1u)) >> 16;
  return (unsigned short)r;
}

__device__ inline unsigned short f2bf_fast(float f) {
  return __builtin_bit_cast(unsigned short, __float2bfloat16(f));
}

__device__ inline float fexp2(float x) { return __builtin_amdgcn_exp2f(x); }

__device__ inline void gload_lds16(const void* g, void* l) {
  __builtin_amdgcn_global_load_lds((const __attribute__((address_space(1))) void*)g,
                                   (__attribute__((address_space(3))) void*)l, 16, 0, 0);
}

// ---------------- fp32 -> bf16 elementwise (+ mask additive table) ----------------
__global__ void k_cvt_bf16(const float* __restrict__ in, unsigned short* __restrict__ out,
                           int n4, const int* __restrict__ mask, float* __restrict__ maskadd,
                           int nmask) {
  const int cvtBlocks = n4 >> 8;
  if ((int)blockIdx.x < cvtBlocks) {
    int i = blockIdx.x * 256 + threadIdx.x;
    float4 v = ((const float4*)in)[i];
    short4v o;
    o[0] = (short)f2bf(v.x); o[1] = (short)f2bf(v.y);
    o[2] = (short)f2bf(v.z); o[3] = (short)f2bf(v.w);
    ((short4v*)out)[i] = o;
  } else {
    int j = (blockIdx.x - cvtBlocks) * 256 + threadIdx.x;
    if (j < nmask) maskadd[j] = mask[j] ? 0.f : -1.0e9f;
  }
}

// ---------------- fp32 [R,C] -> bf16 [C,R] ----------------
__global__ void k_transpose_cvt(const float* __restrict__ in, unsigned short* __restrict__ out,
                                int R, int C) {
  __shared__ float tile[32][33];
  const int tx = threadIdx.x, ty = threadIdx.y;
  const int bc = blockIdx.x * 32, br = blockIdx.y * 32;
#pragma unroll
  for (int i = 0; i < 32; i += 8)
    tile[ty + i][tx] = in[(size_t)(br + ty + i) * C + bc + tx];
  __syncthreads();
#pragma unroll
  for (int i = 0; i < 32; i += 8)
    out[(size_t)(bc + ty + i) * R + br + tx] = f2bf(tile[tx][ty + i]);
}

// ---------------- V slice of qkv -> Vt[B*H, DK, S] ----------------
__global__ __launch_bounds__(256) void k_transpose_v(const unsigned short* __restrict__ qkv,
                                                     unsigned short* __restrict__ vt) {
  const int blk = blockIdx.x;
  const int stile = blk & 31, bh = blk >> 5;
  const int b = bh >> 4, h = bh & 15;
  const int s0 = stile * 64;
  __shared__ alignas(16) unsigned short tile[64][72];
  const int tid = threadIdx.x;
  const unsigned short* src = qkv + (size_t)(b * S + s0) * NQKV + 2 * D + h * DK;
#pragma unroll
  for (int it = 0; it < 2; ++it) {
    const int sl = it * 32 + (tid >> 3);
    const int d0 = (tid & 7) * 8;
    *(short8*)&tile[sl][d0] = *(const short8*)(src + (size_t)sl * NQKV + d0);
  }
  __syncthreads();
  const int d = tid >> 2, sg = tid & 3;
  short8 o0, o1;
#pragma unroll
  for (int j = 0; j < 8; ++j) {
    o0[j] = (short)tile[sg * 16 + j][d];
    o1[j] = (short)tile[sg * 16 + 8 + j][d];
  }
  unsigned short* dst = vt + (size_t)(bh * DK + d) * S + s0 + sg * 16;
  *(short8*)dst = o0;
  *(short8*)(dst + 8) = o1;
}

// ---------------- GEMM: A[M,K] bf16 @ Bt[N,K]^T + bias -> C[M,N] ----------------
template <int OUT_BF16>
__global__ __launch_bounds__(256, 2) void k_gemm(const unsigned short* __restrict__ A,
                                                 const unsigned short* __restrict__ Bt,
                                                 const float* __restrict__ bias,
                                                 void* __restrict__ Cout,
                                                 int M, int N, int K) {
  __shared__ alignas(16) unsigned short As[128 * 64];
  __shared__ alignas(16) unsigned short Bs[128 * 64];
  const int tid = threadIdx.x;
  const int wid = tid >> 6, lane = tid & 63;
  const int lr = lane & 15, lg = lane >> 4;
  const int nbx = N >> 7;
  const int bx = blockIdx.x % nbx, by = blockIdx.x / nbx;
  const int m0 = by << 7, n0 = bx << 7;
  const int wm = (wid >> 1) << 6, wn = (wid & 1) << 6;

  f32x4 acc[4][4] = {};

  const int sk = ((lane & 7) ^ (lane >> 3)) << 4;
  const int srow = lane >> 3;

  const int ktc = K >> 6;
  for (int kt = 0; kt < ktc; ++kt) {
    const int k0 = kt << 6;
    __syncthreads();
#pragma unroll
    for (int c = 0; c < 4; ++c) {
      const int chunk = c * 4 + wid;
      const int mrow = chunk * 8 + srow;
      const char* ga = (const char*)(A + (size_t)(m0 + mrow) * K + k0) + sk;
      gload_lds16(ga, (char*)As + chunk * 1024);
      const char* gb = (const char*)(Bt + (size_t)(n0 + mrow) * K + k0) + sk;
      gload_lds16(gb, (char*)Bs + chunk * 1024);
    }
    __syncthreads();
#pragma unroll
    for (int ks = 0; ks < 2; ++ks) {
      const int kb = ks * 64 + lg * 16;
      const int swz = (lr & 7) << 4;
      short8 af[4], bfr[4];
#pragma unroll
      for (int mf = 0; mf < 4; ++mf) {
        const int m = wm + mf * 16 + lr;
        af[mf] = *(const short8*)((const char*)As + m * 128 + (kb ^ swz));
      }
#pragma unroll
      for (int nf = 0; nf < 4; ++nf) {
        const int n = wn + nf * 16 + lr;
        bfr[nf] = *(const short8*)((const char*)Bs + n * 128 + (kb ^ swz));
      }
#pragma unroll
      for (int mf = 0; mf < 4; ++mf)
#pragma unroll
        for (int nf = 0; nf < 4; ++nf)
          acc[mf][nf] = __builtin_amdgcn_mfma_f32_16x16x32_bf16(af[mf], bfr[nf], acc[mf][nf], 0, 0, 0);
    }
  }
#pragma unroll
  for (int nf = 0; nf < 4; ++nf) {
    const int n = n0 + wn + nf * 16 + lr;
    const float bv = bias[n];
#pragma unroll
    for (int mf = 0; mf < 4; ++mf) {
#pragma unroll
      for (int r = 0; r < 4; ++r) {
        const int m = m0 + wm + mf * 16 + lg * 4 + r;
        const float v = acc[mf][nf][r] + bv;
        if (OUT_BF16)
          ((unsigned short*)Cout)[(size_t)m * N + n] = f2bf(v);
        else
          ((float*)Cout)[(size_t)m * N + n] = v;
      }
    }
  }
}

// ---------------- flash attention v4 ----------------
// grid = B*H*(S/128) = 512 blocks; 8 waves x 16 q rows.
// 3-buffer depth-2 prefetch with counted vmcnt(2) + raw s_barrier (no drain);
// mask table in LDS; defer-max softmax; l-sum reduced once in epilogue.
__global__ __launch_bounds__(512, 4) void k_attn(const unsigned short* __restrict__ qkv,
                                                 const unsigned short* __restrict__ vt,
                                                 const float* __restrict__ maskadd,
                                                 unsigned short* __restrict__ attn) {
  __shared__ alignas(16) char Ks[3][8192];   // [64 keys][128B], xor-swizzled
  __shared__ alignas(16) char Vs[3][8192];   // [64 d][128B keys], xor-swizzled
  __shared__ alignas(16) unsigned short P[8][16][72];
  __shared__ float msk[S];                   // additive mask, log2 domain

  constexpr int NT = S / 64;  // 32 tiles

  const int blk = blockIdx.x;
  // XCD-chunked swizzle (512 = 8*64, bijective)
  const int work = (blk & 7) * 64 + (blk >> 3);
  const int qt = work & 15;
  const int bh = work >> 4;
  const int b = bh >> 4, h = bh & 15;
  const int tid = threadIdx.x;
  const int wid = tid >> 6, lane = tid & 63;
  const int lr = lane & 15, lg = lane >> 4;
  const int q0 = qt * 128 + wid * 16;

  // mask -> LDS (512 threads x float4 = 2048)
  {
    const float4 mv = *(const float4*)(maskadd + b * S + tid * 4);
    *(float4*)&msk[tid * 4] = mv;
  }

  // Q fragments (2 k-slices) in registers
  const unsigned short* qbase = qkv + (size_t)(b * S + q0) * NQKV + h * DK;
  short8 qf[2];
#pragma unroll
  for (int ks = 0; ks < 2; ++ks)
    qf[ks] = *(const short8*)(qbase + (size_t)lr * NQKV + ks * 32 + lg * 8);

  const unsigned short* kg0 = qkv + ((size_t)b * S * NQKV + D + h * DK);
  const unsigned short* vg0 = vt + (size_t)bh * DK * S;
  const int srow = lane >> 3;
  const int sk = ((lane & 7) ^ srow) << 4;

  auto stage = [&](int buf, int kt) {
    const int kbase = kt * 64;
    const int row = wid * 8 + srow;
    gload_lds16((const char*)(kg0 + (size_t)(kbase + row) * NQKV) + sk, Ks[buf] + row * 128);
    gload_lds16((const char*)(vg0 + (size_t)row * S + kbase) + sk, Vs[buf] + row * 128);
  };

  f32x4 o[4] = {};
  float m2[4] = {-1e30f, -1e30f, -1e30f, -1e30f};
  float lpart[4] = {0.f, 0.f, 0.f, 0.f};

  constexpr float C2 = 0.125f * 1.44269504088896f;  // scale * log2(e)
  const int rswz = (lr & 7) << 4;
  unsigned short* pw = &P[wid][0][0];

  // prologue: 2 stages in flight; drain LDS writes of the mask before first barrier
  stage(0, 0);
  stage(1, 1);
  asm volatile("s_waitcnt lgkmcnt(0)" ::: "memory");

  auto compute = [&](int cur, int kt) {
    const int kbase = kt * 64;

    // mask adds from LDS (broadcast across lg groups)
    float add_[4];
#pragma unroll
    for (int kf = 0; kf < 4; ++kf) add_[kf] = msk[kbase + kf * 16 + lr];

    // K B-frags from LDS
    short8 kfr[4][2];
#pragma unroll
    for (int kf = 0; kf < 4; ++kf)
#pragma unroll
      for (int ks = 0; ks < 2; ++ks)
        kfr[kf][ks] = *(const short8*)(Ks[cur] + (kf * 16 + lr) * 128 + ((ks * 64 + lg * 16) ^ rswz));

    // QK^T (log2-domain scores)
    f32x4 sc[4];
#pragma unroll
    for (int kf = 0; kf < 4; ++kf) {
      f32x4 t = {};
      t = __builtin_amdgcn_mfma_f32_16x16x32_bf16(qf[0], kfr[kf][0], t, 0, 0, 0);
      t = __builtin_amdgcn_mfma_f32_16x16x32_bf16(qf[1], kfr[kf][1], t, 0, 0, 0);
      sc[kf] = t;
    }
#pragma unroll
    for (int kf = 0; kf < 4; ++kf)
#pragma unroll
      for (int r = 0; r < 4; ++r)
        sc[kf][r] = sc[kf][r] * C2 + add_[kf];

    // defer-max vote (THR = 6 in log2 domain)
    float pmax[4];
#pragma unroll
    for (int r = 0; r < 4; ++r)
      pmax[r] = fmaxf(fmaxf(sc[0][r], sc[1][r]), fmaxf(sc[2][r], sc[3][r]));
    float worst = fmaxf(fmaxf(pmax[0] - m2[0], pmax[1] - m2[1]),
                        fmaxf(pmax[2] - m2[2], pmax[3] - m2[3]));
    if (!__all(worst <= 6.0f)) {
#pragma unroll
      for (int r = 0; r < 4; ++r) {
        float pm = pmax[r];
#pragma unroll
        for (int off = 1; off < 16; off <<= 1) pm = fmaxf(pm, __shfl_xor(pm, off));
        const float mnew = fmaxf(m2[r], pm);
        const float fac = fexp2(m2[r] - mnew);
        m2[r] = mnew;
        lpart[r] *= fac;
#pragma unroll
        for (int df = 0; df < 4; ++df) o[df][r] *= fac;
      }
    }

    // p = exp2(sc - m)
#pragma unroll
    for (int kf = 0; kf < 4; ++kf)
#pragma unroll
      for (int r = 0; r < 4; ++r) {
        const float p = fexp2(sc[kf][r] - m2[r]);
        sc[kf][r] = p;
        lpart[r] += p;
      }

    // V B-frags (issued before the P round-trip)
    short8 vfr[4][2];
#pragma unroll
    for (int df = 0; df < 4; ++df)
#pragma unroll
      for (int ks = 0; ks < 2; ++ks)
        vfr[df][ks] = *(const short8*)(Vs[cur] + (df * 16 + lr) * 128 + ((ks * 64 + lg * 16) ^ rswz));

    // P -> per-wave LDS (row q, col key), re-read as A-frags
#pragma unroll
    for (int kf = 0; kf < 4; ++kf)
#pragma unroll
      for (int r = 0; r < 4; ++r)
        pw[(lg * 4 + r) * 72 + kf * 16 + lr] = f2bf_fast(sc[kf][r]);
    short8 pa[2];
#pragma unroll
    for (int ks = 0; ks < 2; ++ks)
      pa[ks] = *(const short8*)((const char*)&P[wid][lr][0] + ks * 64 + lg * 16);

    // PV
#pragma unroll
    for (int df = 0; df < 4; ++df) {
      o[df] = __builtin_amdgcn_mfma_f32_16x16x32_bf16(pa[0], vfr[df][0], o[df], 0, 0, 0);
      o[df] = __builtin_amdgcn_mfma_f32_16x16x32_bf16(pa[1], vfr[df][1], o[df], 0, 0, 0);
    }
  };

  int cur = 0;
  for (int kt = 0; kt < NT - 1; ++kt) {
    // stage(kt) is complete once <=2 vmem ops (stage kt+1) remain; never drain to 0
    asm volatile("s_waitcnt vmcnt(2)" ::: "memory");
    __builtin_amdgcn_s_barrier();
    __builtin_amdgcn_sched_barrier(0);
    if (kt + 2 < NT) {
      int nb = cur + 2; if (nb >= 3) nb -= 3;
      stage(nb, kt + 2);
    }
    compute(cur, kt);
    ++cur; if (cur == 3) cur = 0;
  }
  // peeled last tile: no future stages in flight -> full drain
  asm volatile("s_waitcnt vmcnt(0)" ::: "memory");
  __builtin_amdgcn_s_barrier();
  __builtin_amdgcn_sched_barrier(0);
  compute(cur, NT - 1);

  // epilogue: one shfl-reduce of the partial sums, normalize, store
  float lrun[4];
#pragma unroll
  for (int r = 0; r < 4; ++r) {
    float s = lpart[r];
#pragma unroll
    for (int off = 1; off < 16; off <<= 1) s += __shfl_xor(s, off);
    lrun[r] = 1.0f / s;
  }
#pragma unroll
  for (int df = 0; df < 4; ++df)
#pragma unroll
    for (int r = 0; r < 4; ++r) {
      const int q = q0 + lg * 4 + r;
      attn[(size_t)(b * S + q) * D + h * DK + df * 16 + lr] = f2bf(o[df][r] * lrun[r]);
    }
}

extern "C" void kernel_launch(void* const* d_in, const int* in_sizes, int n_in,
                              void* d_out, int out_size, void* d_ws, size_t ws_size,
                              hipStream_t stream) {
  const float* x = (const float*)d_in[0];
  const int* mask = (const int*)d_in[1];
  const float* W_qkv = (const float*)d_in[2];
  const float* b_qkv = (const float*)d_in[3];
  const float* W_out = (const float*)d_in[4];
  const float* b_out = (const float*)d_in[5];
  float* out = (float*)d_out;

  char* ws = (char*)d_ws;
  unsigned short* x_bf   = (unsigned short*)(ws);                          // 8 MB
  unsigned short* wqkv_t = (unsigned short*)(ws + (size_t)(8 << 20));      // 6 MB
  unsigned short* wout_t = (unsigned short*)(ws + (size_t)(14 << 20));     // 2 MB
  unsigned short* qkv    = (unsigned short*)(ws + (size_t)(16 << 20));     // 24 MB
  unsigned short* vtr    = (unsigned short*)(ws + (size_t)(40 << 20));     // 8 MB
  unsigned short* attn   = (unsigned short*)(ws + (size_t)(48 << 20));     // 8 MB
  float*          madd   = (float*)(ws + (size_t)(56 << 20));              // 16 KB

  const int n4 = TOK * D / 4;
  k_cvt_bf16<<<n4 / 256 + (TOK + 255) / 256, 256, 0, stream>>>(x, x_bf, n4, mask, madd, TOK);
  k_transpose_cvt<<<dim3(NQKV / 32, D / 32), dim3(32, 8), 0, stream>>>(W_qkv, wqkv_t, D, NQKV);
  k_transpose_cvt<<<dim3(D / 32, D / 32), dim3(32, 8), 0, stream>>>(W_out, wout_t, D, D);
  k_gemm<1><<<(TOK / 128) * (NQKV / 128), 256, 0, stream>>>(x_bf, wqkv_t, b_qkv, qkv, TOK, NQKV, D);
  k_transpose_v<<<BATCH * H * (S / 64), 256, 0, stream>>>(qkv, vtr);
  k_attn<<<BATCH * H * (S / 128), 512, 0, stream>>>(qkv, vtr, madd, attn);
  k_gemm<0><<<(TOK / 128) * (D / 128), 256, 0, stream>>>(attn, wout_t, b_out, out, TOK, D, D);
}